// Round 2
// baseline (523.003 us; speedup 1.0000x reference)
//
#include <hip/hip_runtime.h>
#include <hip/hip_bf16.h>
#include <math.h>

#define E_TOTAL 800000
#define NODES   50000
#define AF      128
#define NRAD    16
#define OUTF    128
#define KDIM    272
#define KPAD    288   // 9 k-tiles of 32

typedef __attribute__((ext_vector_type(8))) __bf16 bf16x8;
typedef __attribute__((ext_vector_type(8))) short  short8;
typedef __attribute__((ext_vector_type(4))) short  short4v;
typedef __attribute__((ext_vector_type(4))) float  f32x4;

static __device__ __forceinline__ unsigned short f2bf(float f) {
    __hip_bfloat16 h = __float2bfloat16(f);
    return __builtin_bit_cast(unsigned short, h);
}

// ---------- prep: x fp32 -> bf16 ----------
__global__ void k_cvt_x(const float* __restrict__ x, unsigned short* __restrict__ xb) {
    int i = blockIdx.x * 256 + threadIdx.x;           // one float4 per thread
    if (i >= NODES * AF / 4) return;
    float4 v = reinterpret_cast<const float4*>(x)[i];
    short4v o;
    o[0] = (short)f2bf(v.x); o[1] = (short)f2bf(v.y);
    o[2] = (short)f2bf(v.z); o[3] = (short)f2bf(v.w);
    reinterpret_cast<short4v*>(xb)[i] = o;
}

// ---------- prep: W fp32 [272][128] -> bf16 transposed+padded [128][288] ----------
__global__ void k_cvt_w(const float* __restrict__ W, unsigned short* __restrict__ wt) {
    int i = blockIdx.x * 256 + threadIdx.x;
    if (i >= OUTF * KPAD) return;
    int n = i / KPAD, k = i % KPAD;
    wt[i] = f2bf(k < KDIM ? W[(size_t)k * OUTF + n] : 0.0f);
}

// ---------- prep: per-edge bessel RBF -> bf16 [E][16] ----------
__global__ void k_rbf(const int* __restrict__ ei, const float* __restrict__ pos,
                      unsigned short* __restrict__ rb) {
    int e = blockIdx.x * 256 + threadIdx.x;
    if (e >= E_TOTAL) return;
    int s = ei[e], d = ei[E_TOTAL + e];
    float dx = pos[3 * s + 0] - pos[3 * d + 0];
    float dy = pos[3 * s + 1] - pos[3 * d + 1];
    float dz = pos[3 * s + 2] - pos[3 * d + 2];
    float r  = sqrtf(dx * dx + dy * dy + dz * dz);
    float dd = fmaxf(r * (1.0f / 6.0f), 1e-6f);
    float env = 0.0f;
    if (dd < 1.0f) {
        float d2 = dd * dd;
        float d4 = d2 * d2;
        // -(p+1)(p+2)/2 = -21, p(p+2) = 35, -p(p+1)/2 = -15  (p=5)
        env = 1.0f / dd + d4 * (-21.0f + dd * (35.0f - 15.0f * dd));
    }
    float pd = 3.14159265358979323846f * dd;
    short8 p0, p1;
    #pragma unroll
    for (int k = 0; k < 8; ++k) p0[k] = (short)f2bf(env * sinf((float)(k + 1) * pd));
    #pragma unroll
    for (int k = 0; k < 8; ++k) p1[k] = (short)f2bf(env * sinf((float)(k + 9) * pd));
    short8* o = reinterpret_cast<short8*>(rb + (size_t)e * NRAD);
    o[0] = p0; o[1] = p1;
}

// ---------- main GEMM: out[E][128] = silu(A[E][272] @ W[272][128]) ----------
// block tile 128x128, 4 waves (2x2), wave tile 64x64 = 4x4 mfma 16x16x32
__global__ __launch_bounds__(256) void k_gemm(
    const int* __restrict__ ei, const unsigned short* __restrict__ xb,
    const unsigned short* __restrict__ wt, const unsigned short* __restrict__ rb,
    float* __restrict__ out)
{
    __shared__ unsigned short Al[128][40];   // +8 pad: row stride 80B = 20 words -> 2-way
    __shared__ unsigned short Bl[128][40];   // Bl[n][k_in_tile]

    const int tid  = threadIdx.x;
    const int lane = tid & 63;
    const int wid  = tid >> 6;
    const int wrow = wid >> 1, wcol = wid & 1;
    const int e0   = blockIdx.x * 128;

    // staging roles: thread -> (row = tid>>1, 2x16B chunks at elems (tid&1)*16 + {0,8})
    const int ra = tid >> 1;
    const int ca = (tid & 1) * 16;
    const int s   = ei[e0 + ra];
    const int dst = ei[E_TOTAL + e0 + ra];
    const unsigned short* srcp = xb + (size_t)s   * AF;
    const unsigned short* dstp = xb + (size_t)dst * AF;
    const unsigned short* rbp  = rb + (size_t)(e0 + ra) * NRAD;
    const unsigned short* wtp  = wt + (size_t)ra  * KPAD;

    f32x4 acc[4][4];
    #pragma unroll
    for (int m = 0; m < 4; ++m)
        #pragma unroll
        for (int n = 0; n < 4; ++n)
            acc[m][n] = (f32x4)0.0f;

    const int kk = (lane >> 4) * 8;   // k offset within 32-tile for this lane
    const int fr = lane & 15;         // fragment row/col index

    for (int kt = 0; kt < 9; ++kt) {
        const int kb = kt * 32;
        // issue global loads for this k-tile (regs), before the barrier
        short8 a0, a1;
        if (kt < 4) {
            a0 = *reinterpret_cast<const short8*>(srcp + kb + ca);
            a1 = *reinterpret_cast<const short8*>(srcp + kb + ca + 8);
        } else if (kt < 8) {
            a0 = *reinterpret_cast<const short8*>(dstp + kb - AF + ca);
            a1 = *reinterpret_cast<const short8*>(dstp + kb - AF + ca + 8);
        } else if (ca == 0) {          // cols 256..271 = rbf, 272..287 = 0
            a0 = *reinterpret_cast<const short8*>(rbp);
            a1 = *reinterpret_cast<const short8*>(rbp + 8);
        } else {
            a0 = (short8)(short)0;
            a1 = (short8)(short)0;
        }
        short8 b0 = *reinterpret_cast<const short8*>(wtp + kb + ca);
        short8 b1 = *reinterpret_cast<const short8*>(wtp + kb + ca + 8);

        __syncthreads();   // previous tile's reads done
        *reinterpret_cast<short8*>(&Al[ra][ca])     = a0;
        *reinterpret_cast<short8*>(&Al[ra][ca + 8]) = a1;
        *reinterpret_cast<short8*>(&Bl[ra][ca])     = b0;
        *reinterpret_cast<short8*>(&Bl[ra][ca + 8]) = b1;
        __syncthreads();   // this tile visible

        short8 afr[4], bfr[4];
        #pragma unroll
        for (int m = 0; m < 4; ++m)
            afr[m] = *reinterpret_cast<const short8*>(&Al[wrow * 64 + m * 16 + fr][kk]);
        #pragma unroll
        for (int n = 0; n < 4; ++n)
            bfr[n] = *reinterpret_cast<const short8*>(&Bl[wcol * 64 + n * 16 + fr][kk]);
        #pragma unroll
        for (int m = 0; m < 4; ++m)
            #pragma unroll
            for (int n = 0; n < 4; ++n)
                acc[m][n] = __builtin_amdgcn_mfma_f32_16x16x32_bf16(
                    __builtin_bit_cast(bf16x8, afr[m]),
                    __builtin_bit_cast(bf16x8, bfr[n]),
                    acc[m][n], 0, 0, 0);
    }

    // epilogue: silu + store. C/D map: col = lane&15, row = (lane>>4)*4 + reg
    const int rbase = e0 + wrow * 64 + (lane >> 4) * 4;
    const int cbase = wcol * 64 + fr;
    #pragma unroll
    for (int m = 0; m < 4; ++m)
        #pragma unroll
        for (int n = 0; n < 4; ++n)
            #pragma unroll
            for (int r = 0; r < 4; ++r) {
                float v = acc[m][n][r];
                float sv = v / (1.0f + __expf(-v));
                out[(size_t)(rbase + m * 16 + r) * OUTF + cbase + n * 16] = sv;
            }
}

extern "C" void kernel_launch(void* const* d_in, const int* in_sizes, int n_in,
                              void* d_out, int out_size, void* d_ws, size_t ws_size,
                              hipStream_t stream) {
    const float* x   = (const float*)d_in[0];
    const float* pos = (const float*)d_in[1];
    const int*   ei  = (const int*)d_in[2];
    const float* W   = (const float*)d_in[3];
    float* out = (float*)d_out;

    unsigned short* xb  = (unsigned short*)d_ws;          // [50000][128] bf16
    unsigned short* wtb = xb + (size_t)NODES * AF;        // [128][288]  bf16 (W^T padded)
    unsigned short* rbf = wtb + (size_t)OUTF * KPAD;      // [800000][16] bf16

    k_cvt_x<<<(NODES * AF / 4 + 255) / 256, 256, 0, stream>>>(x, xb);
    k_cvt_w<<<(OUTF * KPAD + 255) / 256, 256, 0, stream>>>(W, wtb);
    k_rbf<<<(E_TOTAL + 255) / 256, 256, 0, stream>>>(ei, pos, rbf);
    k_gemm<<<E_TOTAL / 128, 256, 0, stream>>>(ei, xb, wtb, rbf, out);
}